// Round 1
// baseline (92.810 us; speedup 1.0000x reference)
//
#include <hip/hip_runtime.h>

// JPEG-compression-as-augmentation, collapsed to luma-only per-channel codec.
// Chroma planes of a gray (v,v,v) image are exactly 128 and the chroma codec
// is an exact fixed point, so only the Y path survives. Per (B,C) channel:
//   min/max normalize -> *255 -> edge-pad 14x14 -> 16x16 -> 4 blocks of 8x8
//   R = C^T * diffround( C*(X-128)*C^T / (Y_T*f) ) * (Y_T*f) * C + 128
//   out = clip(R,0,255)/255 * rng + min        (f = 0.02 at quality 99)

namespace {

constexpr int CH_PER_WG = 8;   // channels per 256-thread workgroup (32 lanes each)
constexpr int HW        = 196; // 14*14
constexpr int CH_STRIDE = 264; // 4 blocks * 64 + 8 pad words (bank stagger per channel)

// Orthonormal 8-point DCT-II matrix: CM[u][x] = 0.5*alpha_u*cos((2x+1)u*pi/16).
// D = CM*X*CM^T matches DCT_SCALE*einsum; R = CM^T*Q*CM matches 0.25*einsum(Q*ALPHA).
constexpr float CM[8][8] = {
  { 0.35355339059327376f,  0.35355339059327376f,  0.35355339059327376f,  0.35355339059327376f,
    0.35355339059327376f,  0.35355339059327376f,  0.35355339059327376f,  0.35355339059327376f},
  { 0.49039264020161522f,  0.41573480615127262f,  0.27778511650980114f,  0.09754516100806417f,
   -0.09754516100806417f, -0.27778511650980114f, -0.41573480615127262f, -0.49039264020161522f},
  { 0.46193976625564337f,  0.19134171618254492f, -0.19134171618254492f, -0.46193976625564337f,
   -0.46193976625564337f, -0.19134171618254492f,  0.19134171618254492f,  0.46193976625564337f},
  { 0.41573480615127262f, -0.09754516100806417f, -0.49039264020161522f, -0.27778511650980114f,
    0.27778511650980114f,  0.49039264020161522f,  0.09754516100806417f, -0.41573480615127262f},
  { 0.35355339059327376f, -0.35355339059327376f, -0.35355339059327376f,  0.35355339059327376f,
    0.35355339059327376f, -0.35355339059327376f, -0.35355339059327376f,  0.35355339059327376f},
  { 0.27778511650980114f, -0.49039264020161522f,  0.09754516100806417f,  0.41573480615127262f,
   -0.41573480615127262f, -0.09754516100806417f,  0.49039264020161522f, -0.27778511650980114f},
  { 0.19134171618254492f, -0.46193976625564337f,  0.46193976625564337f, -0.19134171618254492f,
   -0.19134171618254492f,  0.46193976625564337f, -0.46193976625564337f,  0.19134171618254492f},
  { 0.09754516100806417f, -0.27778511650980114f,  0.41573480615127262f, -0.49039264020161522f,
    0.49039264020161522f, -0.41573480615127262f,  0.27778511650980114f, -0.09754516100806417f},
};

} // namespace

// Luma quant table (needs memory backing: column index is runtime).
__device__ const float YQTAB[8][8] = {
  {16,11,10,16,24,40,51,61},
  {12,12,14,19,26,58,60,55},
  {14,13,16,24,40,57,69,56},
  {14,17,22,29,51,87,80,62},
  {18,22,37,56,68,109,103,77},
  {24,35,55,64,81,104,113,92},
  {49,64,78,87,103,121,120,101},
  {72,92,95,98,112,100,103,99},
};

__global__ __launch_bounds__(256)
void jpeg_codec_kernel(const float* __restrict__ x, float* __restrict__ out, int ntot) {
  __shared__ float s_raw[CH_PER_WG * HW];
  __shared__ float s_bufA[CH_PER_WG * CH_STRIDE];
  __shared__ float s_bufB[CH_PER_WG * CH_STRIDE];
  __shared__ float s_min[CH_PER_WG];
  __shared__ float s_rng[CH_PER_WG];

  const int tid = threadIdx.x;
  const long long base = (long long)blockIdx.x * (CH_PER_WG * HW);
  const int lim = (int)min((long long)(CH_PER_WG * HW), (long long)ntot - base);

  // ---- 1. coalesced global -> LDS staging (8 channels * 196 floats) ----
  #pragma unroll
  for (int k = 0; k < 7; ++k) {
    int idx = tid + k * 256;
    if (idx < lim) s_raw[idx] = x[base + idx];
  }
  __syncthreads();

  const int ch = tid >> 5;   // local channel 0..7
  const int l  = tid & 31;   // lane-in-channel 0..31 (one 32-lane half-wave)

  // ---- 2. per-channel min/max via half-wave shuffle reduction ----
  {
    float vmin = 1e30f, vmax = -1e30f;
    for (int idx = l; idx < HW; idx += 32) {
      float v = s_raw[ch * HW + idx];
      vmin = fminf(vmin, v);
      vmax = fmaxf(vmax, v);
    }
    #pragma unroll
    for (int off = 16; off; off >>= 1) {   // masks <=16 stay inside the 32-group
      vmin = fminf(vmin, __shfl_xor(vmin, off, 64));
      vmax = fmaxf(vmax, __shfl_xor(vmax, off, 64));
    }
    if (l == 0) { s_min[ch] = vmin; s_rng[ch] = vmax - vmin + 1e-5f; }
  }
  __syncthreads();

  // ---- 3. build edge-padded 16x16, normalized*255-128, block-major layout ----
  {
    const float mn  = s_min[ch];
    const float rng = s_rng[ch];
    #pragma unroll
    for (int k = 0; k < 8; ++k) {
      int p  = l + 32 * k;           // padded flat index 0..255
      int pr = p >> 4, pc = p & 15;
      int sr = pr - 1; sr = sr < 0 ? 0 : (sr > 13 ? 13 : sr);
      int sc = pc - 1; sc = sc < 0 ? 0 : (sc > 13 ? 13 : sc);
      float v = (s_raw[ch * HW + sr * 14 + sc] - mn) / rng * 255.0f - 128.0f;
      int b = ((pr >> 3) << 1) | (pc >> 3);
      s_bufA[ch * CH_STRIDE + b * 64 + (pr & 7) * 8 + (pc & 7)] = v;
    }
  }
  __syncthreads();

  // ---- 4. four separable passes; each: read row i, FMA vs CM, write column i ----
  // pass(M;G) stores G*M^T, so two passes give G*(G*X^T)^T = G*X*G^T.
  const int b    = l >> 3;                                  // block 0..3
  const int i    = l & 7;                                   // row 0..7
  const int src0 = ch * CH_STRIDE + b * 64 + i * 8;         // row i (read)
  const int dst0 = ch * CH_STRIDE + b * 64 + i;             // column i (write)

  float m[8];

  // pass 1: bufB = C * X^T
  #pragma unroll
  for (int j = 0; j < 8; ++j) m[j] = s_bufA[src0 + j];
  #pragma unroll
  for (int k = 0; k < 8; ++k) {
    float s = 0.0f;
    #pragma unroll
    for (int j = 0; j < 8; ++j) s = fmaf(m[j], CM[k][j], s);
    s_bufB[dst0 + 8 * k] = s;
  }
  __syncthreads();

  // pass 2: D = C*X*C^T (lane holds column i of D) + fused quantization
  #pragma unroll
  for (int j = 0; j < 8; ++j) m[j] = s_bufB[src0 + j];
  #pragma unroll
  for (int k = 0; k < 8; ++k) {
    float s = 0.0f;
    #pragma unroll
    for (int j = 0; j < 8; ++j) s = fmaf(m[j], CM[k][j], s);
    float qv = YQTAB[k][i] * 0.02f;        // tab * factor, fp32 like reference
    float xq = s / qv;                     // exact division to match reference
    float r  = rintf(xq);                  // round half to even == jnp.round
    float e  = xq - r;
    s_bufA[dst0 + 8 * k] = (r + e * e * e) * qv;   // Qs in natural layout
  }
  __syncthreads();

  // pass 3: bufB = C^T * Qs^T
  #pragma unroll
  for (int j = 0; j < 8; ++j) m[j] = s_bufA[src0 + j];
  #pragma unroll
  for (int k = 0; k < 8; ++k) {
    float s = 0.0f;
    #pragma unroll
    for (int j = 0; j < 8; ++j) s = fmaf(m[j], CM[j][k], s);
    s_bufB[dst0 + 8 * k] = s;
  }
  __syncthreads();

  // pass 4: bufA = C^T * Qs * C = R (natural layout)
  #pragma unroll
  for (int j = 0; j < 8; ++j) m[j] = s_bufB[src0 + j];
  #pragma unroll
  for (int k = 0; k < 8; ++k) {
    float s = 0.0f;
    #pragma unroll
    for (int j = 0; j < 8; ++j) s = fmaf(m[j], CM[j][k], s);
    s_bufA[dst0 + 8 * k] = s;
  }
  __syncthreads();

  // ---- 5. crop 1:-1, +128, clip, /255, un-normalize, coalesced store ----
  #pragma unroll
  for (int k = 0; k < 7; ++k) {
    int idx = tid + k * 256;
    if (idx < lim) {
      int c2  = idx / HW;
      int rem = idx - c2 * HW;
      int r   = rem / 14;
      int c   = rem - r * 14;
      int pr  = r + 1, pc = c + 1;
      int bb  = ((pr >> 3) << 1) | (pc >> 3);
      float v = s_bufA[c2 * CH_STRIDE + bb * 64 + (pr & 7) * 8 + (pc & 7)] + 128.0f;
      v = v < 0.0f ? 0.0f : (v > 255.0f ? 255.0f : v);
      out[base + idx] = (v / 255.0f) * s_rng[c2] + s_min[c2];
    }
  }
}

extern "C" void kernel_launch(void* const* d_in, const int* in_sizes, int n_in,
                              void* d_out, int out_size, void* d_ws, size_t ws_size,
                              hipStream_t stream) {
  const float* x = (const float*)d_in[0];
  float* out     = (float*)d_out;
  const int ntot = in_sizes[0];                       // 32*1024*14*14
  const int nch  = ntot / HW;                         // 32768 channels
  const int grid = (nch + CH_PER_WG - 1) / CH_PER_WG; // 4096 workgroups
  hipLaunchKernelGGL(jpeg_codec_kernel, dim3(grid), dim3(256), 0, stream,
                     x, out, ntot);
}

// Round 2
// 88.758 us; speedup vs baseline: 1.0457x; 1.0457x over previous
//
#include <hip/hip_runtime.h>

// JPEG-compression-as-augmentation, collapsed to luma-only per-channel codec.
// Chroma planes of a gray (v,v,v) image are exactly 128 and the chroma codec
// is an exact fixed point, so only the Y path survives. Per (B,C) channel:
//   min/max normalize -> *255 -> edge-pad 14x14 -> 16x16 -> 4 blocks of 8x8
//   R = C^T * diffround( C*(X-128)*C^T / (Y_T*f) ) * (Y_T*f) * C + 128
//   out = clip(R,0,255)/255 * rng + min        (f = 0.02 at quality 99)
//
// Round-2 changes vs round-1 (which passed, absmax 1.6e-2):
//  * LDS block layout row-stride 9 / block-stride 72: pass row-reads and
//    column-writes are bank-bijective per 32-lane channel group -> 2 lanes/bank
//    per wave (free) instead of 16-way read conflicts.
//  * 4 of 6 __syncthreads -> wave-level lgkmcnt fences (transposes exchange
//    only within 8 consecutive tids = same wave).
//  * pad/normalize folded into pass-1 reads (removes a stage + barrier).
//  * float4 global load/store (channel size 196 % 4 == 0, bases 16B-aligned).

namespace {

constexpr int CH_PER_WG = 8;   // channels per 256-thread workgroup (32 lanes each)
constexpr int HW        = 196; // 14*14
constexpr int CS        = 288; // per-channel: 4 blocks * (8 rows * stride 9)

// Orthonormal 8-point DCT-II matrix: CM[u][x] = 0.5*alpha_u*cos((2x+1)u*pi/16).
constexpr float CM[8][8] = {
  { 0.35355339059327376f,  0.35355339059327376f,  0.35355339059327376f,  0.35355339059327376f,
    0.35355339059327376f,  0.35355339059327376f,  0.35355339059327376f,  0.35355339059327376f},
  { 0.49039264020161522f,  0.41573480615127262f,  0.27778511650980114f,  0.09754516100806417f,
   -0.09754516100806417f, -0.27778511650980114f, -0.41573480615127262f, -0.49039264020161522f},
  { 0.46193976625564337f,  0.19134171618254492f, -0.19134171618254492f, -0.46193976625564337f,
   -0.46193976625564337f, -0.19134171618254492f,  0.19134171618254492f,  0.46193976625564337f},
  { 0.41573480615127262f, -0.09754516100806417f, -0.49039264020161522f, -0.27778511650980114f,
    0.27778511650980114f,  0.49039264020161522f,  0.09754516100806417f, -0.41573480615127262f},
  { 0.35355339059327376f, -0.35355339059327376f, -0.35355339059327376f,  0.35355339059327376f,
    0.35355339059327376f, -0.35355339059327376f, -0.35355339059327376f,  0.35355339059327376f},
  { 0.27778511650980114f, -0.49039264020161522f,  0.09754516100806417f,  0.41573480615127262f,
   -0.41573480615127262f, -0.09754516100806417f,  0.49039264020161522f, -0.27778511650980114f},
  { 0.19134171618254492f, -0.46193976625564337f,  0.46193976625564337f, -0.19134171618254492f,
   -0.19134171618254492f,  0.46193976625564337f, -0.46193976625564337f,  0.19134171618254492f},
  { 0.09754516100806417f, -0.27778511650980114f,  0.41573480615127262f, -0.49039264020161522f,
    0.49039264020161522f, -0.41573480615127262f,  0.27778511650980114f, -0.09754516100806417f},
};

} // namespace

// Luma quant table (memory-backed: column index is runtime).
__device__ const float YQTAB[8][8] = {
  {16,11,10,16,24,40,51,61},
  {12,12,14,19,26,58,60,55},
  {14,13,16,24,40,57,69,56},
  {14,17,22,29,51,87,80,62},
  {18,22,37,56,68,109,103,77},
  {24,35,55,64,81,104,113,92},
  {49,64,78,87,103,121,120,101},
  {72,92,95,98,112,100,103,99},
};

// Wave-level LDS fence: exchanges are intra-wave (8-lane block transposes);
// DS ops from one wave complete in order, so a drained lgkmcnt + compiler
// memory fence replaces __syncthreads.
#define WAVE_LDS_SYNC() asm volatile("s_waitcnt lgkmcnt(0)" ::: "memory")

__global__ __launch_bounds__(256)
void jpeg_codec_kernel(const float* __restrict__ x, float* __restrict__ out, int ntot) {
  __shared__ __align__(16) float s_raw[CH_PER_WG * HW];   // 6272 B
  __shared__ float s_bufA[CH_PER_WG * CS];                // 9216 B
  __shared__ float s_bufB[CH_PER_WG * CS];                // 9216 B
  __shared__ float s_min[CH_PER_WG];
  __shared__ float s_rng[CH_PER_WG];

  const int tid = threadIdx.x;
  const long long base = (long long)blockIdx.x * (CH_PER_WG * HW);
  const int lim = (int)min((long long)(CH_PER_WG * HW), (long long)ntot - base);

  // ---- 1. coalesced float4 global -> LDS staging (8 ch * 196 floats) ----
  {
    const float4* x4 = (const float4*)(x + base);
    float4* r4 = (float4*)s_raw;
    #pragma unroll
    for (int k = 0; k < 2; ++k) {
      int t = tid + k * 256;
      if (t * 4 + 3 < lim + 1 && t < (CH_PER_WG * HW) / 4) r4[t] = x4[t];
    }
  }
  __syncthreads();

  const int ch = tid >> 5;   // local channel 0..7
  const int l  = tid & 31;   // lane-in-channel 0..31

  // ---- 2. per-channel min/max: float4 reads + full shuffle butterfly ----
  // Butterfly leaves the reduced value in ALL 32 lanes (no LDS broadcast).
  float mn, rng;
  {
    float vmin = 1e30f, vmax = -1e30f;
    const float4* c4 = (const float4*)(s_raw + ch * HW);  // 196*4 B %16 == 0
    #pragma unroll
    for (int k = 0; k < 2; ++k) {
      int t = l + k * 32;
      if (t < HW / 4) {   // 49 float4 per channel
        float4 v = c4[t];
        vmin = fminf(fminf(vmin, v.x), fminf(v.y, fminf(v.z, v.w)));
        vmax = fmaxf(fmaxf(vmax, v.x), fmaxf(v.y, fmaxf(v.z, v.w)));
      }
    }
    #pragma unroll
    for (int off = 16; off; off >>= 1) {   // xor<=16 stays inside the 32-group
      vmin = fminf(vmin, __shfl_xor(vmin, off, 64));
      vmax = fmaxf(vmax, __shfl_xor(vmax, off, 64));
    }
    mn  = vmin;
    rng = vmax - vmin + 1e-5f;
    if (l == 0) { s_min[ch] = mn; s_rng[ch] = rng; }  // for the output phase only
  }

  // ---- 3. four separable passes over stride-9 blocks (bank-conflict-free) ----
  const int b = l >> 3;                       // block 0..3
  const int i = l & 7;                        // row/col 0..7
  const int rbase = ch * CS + b * 72 + i * 9; // row i of block b (contiguous 8)
  const int wbase = ch * CS + b * 72 + i;     // column i (element k at +9k)

  float m[8];

  // pass 1: read padded+normalized X rows straight from s_raw; bufB = C*X^T
  {
    const int pr = ((b >> 1) << 3) + i;       // padded row 0..15
    int sr = pr - 1; sr = sr < 0 ? 0 : (sr > 13 ? 13 : sr);
    const float* rp = s_raw + ch * HW + sr * 14;
    #pragma unroll
    for (int j = 0; j < 8; ++j) {
      int pc = ((b & 1) << 3) + j - 1; pc = pc < 0 ? 0 : (pc > 13 ? 13 : pc);
      m[j] = (rp[pc] - mn) / rng * 255.0f - 128.0f;
    }
    #pragma unroll
    for (int k = 0; k < 8; ++k) {
      float s = 0.0f;
      #pragma unroll
      for (int j = 0; j < 8; ++j) s = fmaf(m[j], CM[k][j], s);
      s_bufB[wbase + 9 * k] = s;
    }
  }
  WAVE_LDS_SYNC();

  // pass 2: D = C*X*C^T (lane holds column i), fused quantization
  #pragma unroll
  for (int j = 0; j < 8; ++j) m[j] = s_bufB[rbase + j];
  #pragma unroll
  for (int k = 0; k < 8; ++k) {
    float s = 0.0f;
    #pragma unroll
    for (int j = 0; j < 8; ++j) s = fmaf(m[j], CM[k][j], s);
    float qv = YQTAB[k][i] * 0.02f;          // tab * factor, fp32 like reference
    float xq = s / qv;                       // exact division to match reference
    float r  = rintf(xq);                    // round half to even == jnp.round
    float e  = xq - r;
    s_bufA[wbase + 9 * k] = (r + e * e * e) * qv;  // Qs in natural layout
  }
  WAVE_LDS_SYNC();

  // pass 3: bufB = (Qs*C)^T
  #pragma unroll
  for (int j = 0; j < 8; ++j) m[j] = s_bufA[rbase + j];
  #pragma unroll
  for (int k = 0; k < 8; ++k) {
    float s = 0.0f;
    #pragma unroll
    for (int j = 0; j < 8; ++j) s = fmaf(m[j], CM[j][k], s);
    s_bufB[wbase + 9 * k] = s;
  }
  WAVE_LDS_SYNC();

  // pass 4: bufA = C^T*Qs*C = R (natural layout)
  #pragma unroll
  for (int j = 0; j < 8; ++j) m[j] = s_bufB[rbase + j];
  #pragma unroll
  for (int k = 0; k < 8; ++k) {
    float s = 0.0f;
    #pragma unroll
    for (int j = 0; j < 8; ++j) s = fmaf(m[j], CM[j][k], s);
    s_bufA[wbase + 9 * k] = s;
  }
  __syncthreads();   // output phase reads across channels (cross-wave)

  // ---- 4. crop 1:-1, +128, clip, /255, un-normalize, float4 store ----
  {
    float4* o4 = (float4*)(out + base);
    #pragma unroll
    for (int k = 0; k < 2; ++k) {
      int t = tid + k * 256;
      if (t < (CH_PER_WG * HW) / 4 && t * 4 + 3 < lim + 1) {
        int idx = 4 * t;
        int c2  = idx / HW;                 // 196 % 4 == 0: one channel per float4
        int rem = idx - c2 * HW;
        int r0  = rem / 14, c0 = rem - 14 * r0;
        float cmn = s_min[c2], crng = s_rng[c2];
        float vals[4];
        #pragma unroll
        for (int q = 0; q < 4; ++q) {
          int rr = r0, cc = c0 + q;
          if (cc >= 14) { cc -= 14; ++rr; }  // crosses a row boundary at most once
          int pr = rr + 1, pc = cc + 1;
          int bb = ((pr >> 3) << 1) | (pc >> 3);
          float v = s_bufA[c2 * CS + bb * 72 + (pr & 7) * 9 + (pc & 7)] + 128.0f;
          v = v < 0.0f ? 0.0f : (v > 255.0f ? 255.0f : v);
          vals[q] = v / 255.0f * crng + cmn;
        }
        o4[t] = make_float4(vals[0], vals[1], vals[2], vals[3]);
      }
    }
  }
}

extern "C" void kernel_launch(void* const* d_in, const int* in_sizes, int n_in,
                              void* d_out, int out_size, void* d_ws, size_t ws_size,
                              hipStream_t stream) {
  const float* x = (const float*)d_in[0];
  float* out     = (float*)d_out;
  const int ntot = in_sizes[0];                       // 32*1024*14*14
  const int nch  = ntot / HW;                         // 32768 channels
  const int grid = (nch + CH_PER_WG - 1) / CH_PER_WG; // 4096 workgroups
  hipLaunchKernelGGL(jpeg_codec_kernel, dim3(grid), dim3(256), 0, stream,
                     x, out, ntot);
}

// Round 3
// 84.286 us; speedup vs baseline: 1.1011x; 1.0531x over previous
//
#include <hip/hip_runtime.h>

// JPEG-compression-as-augmentation, collapsed to luma-only per-channel codec.
// Chroma planes of a gray (v,v,v) image are exactly 128 and the chroma codec
// is an exact fixed point, so only the Y path survives. Per (B,C) channel:
//   min/max normalize -> *255 -> edge-pad 14x14 -> 16x16 -> 4 blocks of 8x8
//   R = C^T * diffround( C*(X-128)*C^T / (Y_T*f) ) * (Y_T*f) * C + 128
//   out = clip(R,0,255)/255 * rng + min        (f = 0.02 at quality 99)
//
// Round-3 changes vs round-2 (passed, absmax 1.6e-2, dur 88.8):
//  * divide elimination: normalize uses inv=255/rng (8 div -> 1/thread),
//    output uses rng*(1/255) scale (4 div -> 0). Quant keeps the EXACT
//    divide s/qv — it feeds rintf and is round-boundary sensitive.
//  * dead bounds guards removed (ntot = 4096 WGs * 1568 exactly).
// Round-2 retained: stride-9/72 bank-bijective LDS layout (pass R/W are
// 2 lanes/bank = free), wave-level lgkmcnt fences for intra-wave transposes,
// float4 global I/O.

namespace {

constexpr int CH_PER_WG = 8;   // channels per 256-thread workgroup (32 lanes each)
constexpr int HW        = 196; // 14*14
constexpr int CS        = 288; // per-channel: 4 blocks * (8 rows * stride 9)

// Orthonormal 8-point DCT-II matrix: CM[u][x] = 0.5*alpha_u*cos((2x+1)u*pi/16).
constexpr float CM[8][8] = {
  { 0.35355339059327376f,  0.35355339059327376f,  0.35355339059327376f,  0.35355339059327376f,
    0.35355339059327376f,  0.35355339059327376f,  0.35355339059327376f,  0.35355339059327376f},
  { 0.49039264020161522f,  0.41573480615127262f,  0.27778511650980114f,  0.09754516100806417f,
   -0.09754516100806417f, -0.27778511650980114f, -0.41573480615127262f, -0.49039264020161522f},
  { 0.46193976625564337f,  0.19134171618254492f, -0.19134171618254492f, -0.46193976625564337f,
   -0.46193976625564337f, -0.19134171618254492f,  0.19134171618254492f,  0.46193976625564337f},
  { 0.41573480615127262f, -0.09754516100806417f, -0.49039264020161522f, -0.27778511650980114f,
    0.27778511650980114f,  0.49039264020161522f,  0.09754516100806417f, -0.41573480615127262f},
  { 0.35355339059327376f, -0.35355339059327376f, -0.35355339059327376f,  0.35355339059327376f,
    0.35355339059327376f, -0.35355339059327376f, -0.35355339059327376f,  0.35355339059327376f},
  { 0.27778511650980114f, -0.49039264020161522f,  0.09754516100806417f,  0.41573480615127262f,
   -0.41573480615127262f, -0.09754516100806417f,  0.49039264020161522f, -0.27778511650980114f},
  { 0.19134171618254492f, -0.46193976625564337f,  0.46193976625564337f, -0.19134171618254492f,
   -0.19134171618254492f,  0.46193976625564337f, -0.46193976625564337f,  0.19134171618254492f},
  { 0.09754516100806417f, -0.27778511650980114f,  0.41573480615127262f, -0.49039264020161522f,
    0.49039264020161522f, -0.41573480615127262f,  0.27778511650980114f, -0.09754516100806417f},
};

} // namespace

// Luma quant table (memory-backed: column index is runtime per-lane).
__device__ const float YQTAB[8][8] = {
  {16,11,10,16,24,40,51,61},
  {12,12,14,19,26,58,60,55},
  {14,13,16,24,40,57,69,56},
  {14,17,22,29,51,87,80,62},
  {18,22,37,56,68,109,103,77},
  {24,35,55,64,81,104,113,92},
  {49,64,78,87,103,121,120,101},
  {72,92,95,98,112,100,103,99},
};

// Wave-level LDS fence: transposes exchange only within 8 consecutive tids
// (same wave); one wave's DS ops complete in order, so a drained lgkmcnt +
// compiler memory fence replaces __syncthreads.
#define WAVE_LDS_SYNC() asm volatile("s_waitcnt lgkmcnt(0)" ::: "memory")

__global__ __launch_bounds__(256)
void jpeg_codec_kernel(const float* __restrict__ x, float* __restrict__ out) {
  __shared__ __align__(16) float s_raw[CH_PER_WG * HW];   // 6272 B
  __shared__ float s_bufA[CH_PER_WG * CS];                // 9216 B
  __shared__ float s_bufB[CH_PER_WG * CS];                // 9216 B
  __shared__ float s_min[CH_PER_WG];
  __shared__ float s_scale[CH_PER_WG];                    // rng * (1/255)

  const int tid = threadIdx.x;
  const long long base = (long long)blockIdx.x * (CH_PER_WG * HW);

  // ---- 1. coalesced float4 global -> LDS staging (8 ch * 196 = 392 f4) ----
  {
    const float4* x4 = (const float4*)(x + base);
    float4* r4 = (float4*)s_raw;
    r4[tid & 255] = x4[tid & 255];            // 0..255
    int t = tid + 256;                        // 256..511
    if (t < (CH_PER_WG * HW) / 4) r4[t] = x4[t];
  }
  __syncthreads();

  const int ch = tid >> 5;   // local channel 0..7
  const int l  = tid & 31;   // lane-in-channel 0..31

  // ---- 2. per-channel min/max: float4 reads + shuffle butterfly ----
  float mn, inv;             // inv = 255/rng (the ONLY normalize divide)
  {
    float vmin = 1e30f, vmax = -1e30f;
    const float4* c4 = (const float4*)(s_raw + ch * HW);  // 196*4 B % 16 == 0
    {
      float4 v = c4[l];                       // lanes 0..31 -> f4 0..31
      vmin = fminf(fminf(vmin, v.x), fminf(v.y, fminf(v.z, v.w)));
      vmax = fmaxf(fmaxf(vmax, v.x), fmaxf(v.y, fmaxf(v.z, v.w)));
    }
    if (l < 17) {                             // f4 32..48 (49 per channel)
      float4 v = c4[l + 32];
      vmin = fminf(fminf(vmin, v.x), fminf(v.y, fminf(v.z, v.w)));
      vmax = fmaxf(fmaxf(vmax, v.x), fmaxf(v.y, fmaxf(v.z, v.w)));
    }
    #pragma unroll
    for (int off = 16; off; off >>= 1) {      // xor<=16 stays inside the 32-group
      vmin = fminf(vmin, __shfl_xor(vmin, off, 64));
      vmax = fmaxf(vmax, __shfl_xor(vmax, off, 64));
    }
    mn = vmin;
    float rng = vmax - vmin + 1e-5f;
    inv = 255.0f / rng;
    if (l == 0) { s_min[ch] = mn; s_scale[ch] = rng * (1.0f / 255.0f); }
  }

  // ---- 3. four separable passes over stride-9 blocks (bank-conflict-free) ----
  const int b = l >> 3;                       // block 0..3
  const int i = l & 7;                        // row/col 0..7
  const int rbase = ch * CS + b * 72 + i * 9; // row i of block b (contiguous 8)
  const int wbase = ch * CS + b * 72 + i;     // column i (element k at +9k)

  float m[8];

  // pass 1: read padded+normalized X rows straight from s_raw; bufB = C*X^T
  {
    const int pr = ((b >> 1) << 3) + i;       // padded row 0..15
    int sr = pr - 1; sr = sr < 0 ? 0 : (sr > 13 ? 13 : sr);
    const float* rp = s_raw + ch * HW + sr * 14;
    #pragma unroll
    for (int j = 0; j < 8; ++j) {
      int pc = ((b & 1) << 3) + j - 1; pc = pc < 0 ? 0 : (pc > 13 ? 13 : pc);
      m[j] = fmaf(rp[pc] - mn, inv, -128.0f);
    }
    #pragma unroll
    for (int k = 0; k < 8; ++k) {
      float s = 0.0f;
      #pragma unroll
      for (int j = 0; j < 8; ++j) s = fmaf(m[j], CM[k][j], s);
      s_bufB[wbase + 9 * k] = s;
    }
  }
  WAVE_LDS_SYNC();

  // pass 2: D = C*X*C^T (lane holds column i), fused quantization.
  // s/qv stays an EXACT division: it feeds rintf and round-boundary flips
  // cost up to ~0.06 absmax each — don't trade ulps here.
  #pragma unroll
  for (int j = 0; j < 8; ++j) m[j] = s_bufB[rbase + j];
  #pragma unroll
  for (int k = 0; k < 8; ++k) {
    float s = 0.0f;
    #pragma unroll
    for (int j = 0; j < 8; ++j) s = fmaf(m[j], CM[k][j], s);
    float qv = YQTAB[k][i] * 0.02f;          // tab * factor, fp32 like reference
    float xq = s / qv;
    float r  = rintf(xq);                    // round half to even == jnp.round
    float e  = xq - r;
    s_bufA[wbase + 9 * k] = (r + e * e * e) * qv;  // Qs in natural layout
  }
  WAVE_LDS_SYNC();

  // pass 3: bufB = (Qs*C)^T
  #pragma unroll
  for (int j = 0; j < 8; ++j) m[j] = s_bufA[rbase + j];
  #pragma unroll
  for (int k = 0; k < 8; ++k) {
    float s = 0.0f;
    #pragma unroll
    for (int j = 0; j < 8; ++j) s = fmaf(m[j], CM[j][k], s);
    s_bufB[wbase + 9 * k] = s;
  }
  WAVE_LDS_SYNC();

  // pass 4: bufA = C^T*Qs*C = R (natural layout)
  #pragma unroll
  for (int j = 0; j < 8; ++j) m[j] = s_bufB[rbase + j];
  #pragma unroll
  for (int k = 0; k < 8; ++k) {
    float s = 0.0f;
    #pragma unroll
    for (int j = 0; j < 8; ++j) s = fmaf(m[j], CM[j][k], s);
    s_bufA[wbase + 9 * k] = s;
  }
  __syncthreads();   // output phase reads across channels (cross-wave)

  // ---- 4. crop 1:-1, +128, clip, un-normalize (divide-free), float4 store ----
  {
    float4* o4 = (float4*)(out + base);
    #pragma unroll
    for (int k = 0; k < 2; ++k) {
      int t = tid + k * 256;
      if (t < (CH_PER_WG * HW) / 4) {
        int idx = 4 * t;
        int c2  = idx / HW;                 // 196 % 4 == 0: one channel per float4
        int rem = idx - c2 * HW;
        int r0  = rem / 14, c0 = rem - 14 * r0;
        float cmn = s_min[c2], cscale = s_scale[c2];
        float vals[4];
        #pragma unroll
        for (int q = 0; q < 4; ++q) {
          int rr = r0, cc = c0 + q;
          if (cc >= 14) { cc -= 14; ++rr; }  // crosses a row boundary at most once
          int pr = rr + 1, pc = cc + 1;
          int bb = ((pr >> 3) << 1) | (pc >> 3);
          float v = s_bufA[c2 * CS + bb * 72 + (pr & 7) * 9 + (pc & 7)] + 128.0f;
          v = v < 0.0f ? 0.0f : (v > 255.0f ? 255.0f : v);
          vals[q] = fmaf(v, cscale, cmn);
        }
        o4[t] = make_float4(vals[0], vals[1], vals[2], vals[3]);
      }
    }
  }
}

extern "C" void kernel_launch(void* const* d_in, const int* in_sizes, int n_in,
                              void* d_out, int out_size, void* d_ws, size_t ws_size,
                              hipStream_t stream) {
  const float* x = (const float*)d_in[0];
  float* out     = (float*)d_out;
  const int ntot = in_sizes[0];                       // 32*1024*14*14
  const int nch  = ntot / HW;                         // 32768 channels
  const int grid = (nch + CH_PER_WG - 1) / CH_PER_WG; // 4096 workgroups
  hipLaunchKernelGGL(jpeg_codec_kernel, dim3(grid), dim3(256), 0, stream,
                     x, out);
}

// Round 4
// 83.540 us; speedup vs baseline: 1.1110x; 1.0089x over previous
//
#include <hip/hip_runtime.h>

// JPEG-compression-as-augmentation, collapsed to luma-only per-channel codec.
// Chroma planes of a gray (v,v,v) image are exactly 128 and the chroma codec
// is an exact fixed point, so only the Y path survives. Per (B,C) channel:
//   min/max normalize -> *255 -> edge-pad 14x14 -> 16x16 -> 4 blocks of 8x8
//   R = C^T * diffround( C*(X-128)*C^T / (Y_T*f) ) * (Y_T*f) * C + 128
//   out = clip(R,0,255)/255 * rng + min        (f = 0.02 at quality 99)
//
// Round-4 changes vs round-3 (passed, absmax 1.6e-2, dur 84.3):
//  * BARRIER-FREE: each wave owns 2 whole channels end-to-end (staging, codec,
//    output all per-wave, still fully coalesced) -> zero __syncthreads; all
//    sync is intra-wave s_waitcnt fences.
//  * async staging via global_load_lds width=16 (lane-contiguous layout is
//    exactly the instruction's wave-uniform-base + lane*16 constraint).
//  * raw input aliased into bufA's per-wave region (dead after pass 1, which
//    completes before pass-2 writes under the wave fence): LDS 24.7->18.4 KB
//    -> 8 blocks/CU -> 32 waves/CU (max occupancy).
//  * s_min/s_scale LDS arrays replaced by 4 shuffle broadcasts.
// Retained: stride-9/72 bank-bijective block layout (pass R/W 2 lanes/bank =
// free), exact fp32 quant divide (round-boundary sensitive), divide-free
// normalize/output, float4 global I/O.

namespace {

constexpr int CH_PER_WG = 8;   // 4 waves * 2 channels
constexpr int HW        = 196; // 14*14
constexpr int CS        = 288; // per-channel block storage: 4 blocks * (8 rows * stride 9)
constexpr int WREG      = 2 * CS; // per-wave region (2 channels) in each buffer

// Orthonormal 8-point DCT-II matrix: CM[u][x] = 0.5*alpha_u*cos((2x+1)u*pi/16).
constexpr float CM[8][8] = {
  { 0.35355339059327376f,  0.35355339059327376f,  0.35355339059327376f,  0.35355339059327376f,
    0.35355339059327376f,  0.35355339059327376f,  0.35355339059327376f,  0.35355339059327376f},
  { 0.49039264020161522f,  0.41573480615127262f,  0.27778511650980114f,  0.09754516100806417f,
   -0.09754516100806417f, -0.27778511650980114f, -0.41573480615127262f, -0.49039264020161522f},
  { 0.46193976625564337f,  0.19134171618254492f, -0.19134171618254492f, -0.46193976625564337f,
   -0.46193976625564337f, -0.19134171618254492f,  0.19134171618254492f,  0.46193976625564337f},
  { 0.41573480615127262f, -0.09754516100806417f, -0.49039264020161522f, -0.27778511650980114f,
    0.27778511650980114f,  0.49039264020161522f,  0.09754516100806417f, -0.41573480615127262f},
  { 0.35355339059327376f, -0.35355339059327376f, -0.35355339059327376f,  0.35355339059327376f,
    0.35355339059327376f, -0.35355339059327376f, -0.35355339059327376f,  0.35355339059327376f},
  { 0.27778511650980114f, -0.49039264020161522f,  0.09754516100806417f,  0.41573480615127262f,
   -0.41573480615127262f, -0.09754516100806417f,  0.49039264020161522f, -0.27778511650980114f},
  { 0.19134171618254492f, -0.46193976625564337f,  0.46193976625564337f, -0.19134171618254492f,
   -0.19134171618254492f,  0.46193976625564337f, -0.46193976625564337f,  0.19134171618254492f},
  { 0.09754516100806417f, -0.27778511650980114f,  0.41573480615127262f, -0.49039264020161522f,
    0.49039264020161522f, -0.41573480615127262f,  0.27778511650980114f, -0.09754516100806417f},
};

} // namespace

// Luma quant table (memory-backed: column index is runtime per-lane).
__device__ const float YQTAB[8][8] = {
  {16,11,10,16,24,40,51,61},
  {12,12,14,19,26,58,60,55},
  {14,13,16,24,40,57,69,56},
  {14,17,22,29,51,87,80,62},
  {18,22,37,56,68,109,103,77},
  {24,35,55,64,81,104,113,92},
  {49,64,78,87,103,121,120,101},
  {72,92,95,98,112,100,103,99},
};

// Intra-wave fences: one wave's DS (resp. VMEM->LDS) ops complete in order
// w.r.t. its own later ops after the counter drains; with all producers and
// consumers in the same wave, no s_barrier is needed anywhere.
#define WAVE_LDS_SYNC() asm volatile("s_waitcnt lgkmcnt(0)" ::: "memory")
#define WAVE_VM_SYNC()  asm volatile("s_waitcnt vmcnt(0)" ::: "memory")

typedef __attribute__((address_space(1))) const void gvoid_t;
typedef __attribute__((address_space(3))) void       lvoid_t;

__global__ __launch_bounds__(256)
void jpeg_codec_kernel(const float* __restrict__ x, float* __restrict__ out) {
  __shared__ __align__(16) float s_A[CH_PER_WG * CS];   // 9216 B (also hosts raw input)
  __shared__ __align__(16) float s_B[CH_PER_WG * CS];   // 9216 B

  const int tid = threadIdx.x;
  const int w   = tid >> 6;       // wave 0..3
  const int wl  = tid & 63;       // lane in wave
  const int chl = (tid >> 5) & 1; // channel-in-wave 0/1
  const int l   = tid & 31;       // lane-in-channel

  // wave w owns global float4 range [g4, g4+98) = 2 channels of 49 f4 each
  const long long g4 = (long long)blockIdx.x * (CH_PER_WG * HW / 4) + w * (2 * HW / 4);

  // ---- 1. per-wave async staging: raw -> bufA[w*WREG .. +392) ----
  // global_load_lds writes lane i's 16B to (uniform lds base) + i*16, which is
  // exactly the contiguous layout we want. raw floats [0,392) of the wave
  // region; ch0 raw = [0,196), ch1 raw = [196,392).
  {
    const float4* x4 = (const float4*)x + g4;
    float* raw = s_A + w * WREG;
    __builtin_amdgcn_global_load_lds((gvoid_t*)(x4 + wl), (lvoid_t*)raw, 16, 0, 0);
    if (wl < 2 * HW / 4 - 64)  // lanes 0..33 stage f4 64..97
      __builtin_amdgcn_global_load_lds((gvoid_t*)(x4 + 64 + wl),
                                       (lvoid_t*)(raw + 256), 16, 0, 0);
  }
  WAVE_VM_SYNC();

  const float* raw_ch = s_A + w * WREG + chl * HW;  // this lane's channel raw

  // ---- 2. per-channel min/max: float4 reads + shuffle butterfly ----
  float mn, inv;                 // inv = 255/rng (the only normalize divide)
  float mn0, mn1, sc0, sc1;      // both channels' params, broadcast wave-wide
  {
    float vmin = 1e30f, vmax = -1e30f;
    const float4* c4 = (const float4*)raw_ch;       // offsets %16 == 0
    {
      float4 v = c4[l];                             // f4 0..31
      vmin = fminf(fminf(vmin, v.x), fminf(v.y, fminf(v.z, v.w)));
      vmax = fmaxf(fmaxf(vmax, v.x), fmaxf(v.y, fmaxf(v.z, v.w)));
    }
    if (l < 17) {                                   // f4 32..48
      float4 v = c4[l + 32];
      vmin = fminf(fminf(vmin, v.x), fminf(v.y, fminf(v.z, v.w)));
      vmax = fmaxf(fmaxf(vmax, v.x), fmaxf(v.y, fmaxf(v.z, v.w)));
    }
    #pragma unroll
    for (int off = 16; off; off >>= 1) {            // xor<=16 stays in 32-group
      vmin = fminf(vmin, __shfl_xor(vmin, off, 64));
      vmax = fmaxf(vmax, __shfl_xor(vmax, off, 64));
    }
    mn = vmin;
    float rng   = vmax - vmin + 1e-5f;
    inv         = 255.0f / rng;
    float scale = rng * (1.0f / 255.0f);
    mn0 = __shfl(mn, 0, 64);  mn1 = __shfl(mn, 32, 64);
    sc0 = __shfl(scale, 0, 64); sc1 = __shfl(scale, 32, 64);
  }

  // ---- 3. four separable passes over stride-9 blocks (bank-bijective) ----
  const int b = l >> 3;                          // block 0..3
  const int i = l & 7;                           // row/col 0..7
  const int cbase = w * WREG + chl * CS;         // channel block-storage base
  const int rbase = cbase + b * 72 + i * 9;      // row i of block b (contig 8)
  const int wbase = cbase + b * 72 + i;          // column i (element k at +9k)

  float m[8];

  // pass 1: read padded+normalized X rows straight from raw; bufB = C*X^T
  {
    const int pr = ((b >> 1) << 3) + i;          // padded row 0..15
    int sr = pr - 1; sr = sr < 0 ? 0 : (sr > 13 ? 13 : sr);
    const float* rp = raw_ch + sr * 14;
    #pragma unroll
    for (int j = 0; j < 8; ++j) {
      int pc = ((b & 1) << 3) + j - 1; pc = pc < 0 ? 0 : (pc > 13 ? 13 : pc);
      m[j] = fmaf(rp[pc] - mn, inv, -128.0f);
    }
    #pragma unroll
    for (int k = 0; k < 8; ++k) {
      float s = 0.0f;
      #pragma unroll
      for (int j = 0; j < 8; ++j) s = fmaf(m[j], CM[k][j], s);
      s_B[wbase + 9 * k] = s;
    }
  }
  WAVE_LDS_SYNC();   // also orders: raw fully read before pass 2 clobbers it

  // pass 2: D = C*X*C^T (lane holds column i), fused quantization.
  // s/qv stays an EXACT division: it feeds rintf; round-boundary flips cost
  // up to ~0.08 absmax each — don't trade ulps here. Writes bufA (raw dead).
  #pragma unroll
  for (int j = 0; j < 8; ++j) m[j] = s_B[rbase + j];
  #pragma unroll
  for (int k = 0; k < 8; ++k) {
    float s = 0.0f;
    #pragma unroll
    for (int j = 0; j < 8; ++j) s = fmaf(m[j], CM[k][j], s);
    float qv = YQTAB[k][i] * 0.02f;              // tab * factor, fp32 as reference
    float xq = s / qv;
    float r  = rintf(xq);                        // round half to even == jnp.round
    float e  = xq - r;
    s_A[wbase + 9 * k] = (r + e * e * e) * qv;   // Qs in natural layout
  }
  WAVE_LDS_SYNC();

  // pass 3: bufB = (Qs*C)^T
  #pragma unroll
  for (int j = 0; j < 8; ++j) m[j] = s_A[rbase + j];
  #pragma unroll
  for (int k = 0; k < 8; ++k) {
    float s = 0.0f;
    #pragma unroll
    for (int j = 0; j < 8; ++j) s = fmaf(m[j], CM[j][k], s);
    s_B[wbase + 9 * k] = s;
  }
  WAVE_LDS_SYNC();

  // pass 4: bufA = C^T*Qs*C = R (natural layout)
  #pragma unroll
  for (int j = 0; j < 8; ++j) m[j] = s_B[rbase + j];
  #pragma unroll
  for (int k = 0; k < 8; ++k) {
    float s = 0.0f;
    #pragma unroll
    for (int j = 0; j < 8; ++j) s = fmaf(m[j], CM[j][k], s);
    s_A[wbase + 9 * k] = s;
  }
  WAVE_LDS_SYNC();   // wave-local: output reads only this wave's channels

  // ---- 4. crop 1:-1, +128, clip, un-normalize, per-wave float4 store ----
  {
    float4* o4 = (float4*)out + g4;
    #pragma unroll
    for (int k = 0; k < 2; ++k) {
      int t = wl + k * 64;                       // f4 index within wave's 98
      if (t < 2 * HW / 4) {
        int idx = 4 * t;                         // float index within 392
        int c2l = idx / HW;                      // local channel 0/1
        int rem = idx - c2l * HW;
        int r0  = rem / 14, c0 = rem - 14 * r0;
        float cmn = c2l ? mn1 : mn0;
        float csc = c2l ? sc1 : sc0;
        const float* blk = s_A + w * WREG + c2l * CS;
        float vals[4];
        #pragma unroll
        for (int q = 0; q < 4; ++q) {
          int rr = r0, cc = c0 + q;
          if (cc >= 14) { cc -= 14; ++rr; }      // crosses a row at most once
          int pr = rr + 1, pc = cc + 1;
          int bb = ((pr >> 3) << 1) | (pc >> 3);
          float v = blk[bb * 72 + (pr & 7) * 9 + (pc & 7)] + 128.0f;
          v = v < 0.0f ? 0.0f : (v > 255.0f ? 255.0f : v);
          vals[q] = fmaf(v, csc, cmn);
        }
        o4[t] = make_float4(vals[0], vals[1], vals[2], vals[3]);
      }
    }
  }
}

extern "C" void kernel_launch(void* const* d_in, const int* in_sizes, int n_in,
                              void* d_out, int out_size, void* d_ws, size_t ws_size,
                              hipStream_t stream) {
  const float* x = (const float*)d_in[0];
  float* out     = (float*)d_out;
  const int ntot = in_sizes[0];                       // 32*1024*14*14
  const int nch  = ntot / HW;                         // 32768 channels
  const int grid = (nch + CH_PER_WG - 1) / CH_PER_WG; // 4096 workgroups
  hipLaunchKernelGGL(jpeg_codec_kernel, dim3(grid), dim3(256), 0, stream,
                     x, out);
}